// Round 4
// baseline (776.300 us; speedup 1.0000x reference)
//
#include <hip/hip_runtime.h>

// Problem constants (match the JAX reference)
#define MAXVAL   5843
#define TOP_K    200
#define STEP_SZ  30
#define N_STEPS  189      // ceil((5843-200)/30)
#define BATCH    4

// v4b: single fused dispatch. One 64-lane wave per row:
//   phase 1: softmax stats over the 200-wide window [start, start+200),
//            start = min(q,188)*30  (registers only, two wave reductions)
//   phase 2: write the 200 window probabilities straight from registers
//   phase 3: zero [0,start) and [wend,MAXVAL) with tight branch-free
//            16B nontemporal-store loops
// Masked entries of the reference softmax underflow to exactly 0.0f in fp32,
// so literal zeros are exact. Every output byte is written exactly once by
// the wave that owns its row -> no inter-block ordering hazard, no memset.
//
// v4 fix: __builtin_nontemporal_store requires a clang ext_vector type, not
// HIP's float4 class. Use f32x4 = float ext_vector_type(4).

typedef float f32x4 __attribute__((ext_vector_type(4)));

__device__ __forceinline__ void zero_range(float* __restrict__ p, int n,
                                           const int lane) {
    if (n <= 0) return;
    // Scalar head up to 16B alignment.
    const int mis  = (int)(((uintptr_t)p >> 2) & 3);
    int head = (4 - mis) & 3;
    if (head > n) head = n;
    if (lane < head) p[lane] = 0.0f;
    p += head; n -= head;

    // Branch-free 16B body (lane-strided, 1 KiB per wave-instruction).
    const int nq = n >> 2;
    f32x4* q4 = (f32x4*)p;
    const f32x4 z = {0.0f, 0.0f, 0.0f, 0.0f};
    for (int i = lane; i < nq; i += 64)
        __builtin_nontemporal_store(z, q4 + i);

    // Scalar tail.
    const int tail = n & 3;
    if (lane < tail) p[(nq << 2) + lane] = 0.0f;
}

__global__ __launch_bounds__(256) void fused_window_softmax(
        const float* __restrict__ X, float* __restrict__ Out) {
    const int gtid  = blockIdx.x * blockDim.x + threadIdx.x;
    const int wave  = gtid >> 6;          // global wave id == row id
    const int lane  = gtid & 63;
    const int nrows = BATCH * MAXVAL;
    if (wave >= nrows) return;

    const int q     = wave % MAXVAL;
    const int start = (q < N_STEPS - 1 ? q : N_STEPS - 1) * STEP_SZ;
    const int wend  = start + TOP_K;

    const size_t row_off = (size_t)wave * MAXVAL;
    const float* xwin = X + row_off + start;
    float*       orow = Out + row_off;

    // ---- Phase 1: stats over the 200-wide window (200 = 3*64 + 8) ----
    float v[4];
    float m = -1e30f;
#pragma unroll
    for (int k = 0; k < 4; ++k) {
        const int idx = lane + 64 * k;
        v[k] = (idx < TOP_K) ? xwin[idx] : -1e30f;
        m = fmaxf(m, v[k]);
    }
#pragma unroll
    for (int off = 32; off > 0; off >>= 1)
        m = fmaxf(m, __shfl_xor(m, off, 64));

    float s = 0.0f;
#pragma unroll
    for (int k = 0; k < 4; ++k) {
        const int idx = lane + 64 * k;
        v[k] = (idx < TOP_K) ? __expf(v[k] - m) : 0.0f;
        s += v[k];
    }
#pragma unroll
    for (int off = 32; off > 0; off >>= 1)
        s += __shfl_xor(s, off, 64);

    const float inv = 1.0f / s;   // wave-uniform

    // ---- Phase 2: window probabilities straight from registers ----
#pragma unroll
    for (int k = 0; k < 4; ++k) {
        const int idx = lane + 64 * k;
        if (idx < TOP_K) orow[start + idx] = v[k] * inv;
    }

    // ---- Phase 3: zeros outside the window ----
    zero_range(orow, start, lane);                    // [0, start)
    zero_range(orow + wend, MAXVAL - wend, lane);     // [wend, MAXVAL)
}

extern "C" void kernel_launch(void* const* d_in, const int* in_sizes, int n_in,
                              void* d_out, int out_size, void* d_ws, size_t ws_size,
                              hipStream_t stream) {
    const float* X = (const float*)d_in[0];
    float* out = (float*)d_out;

    const int nrows = BATCH * MAXVAL;            // 23372
    const int waves_per_block = 4;               // 256 threads
    const int blocks = (nrows + waves_per_block - 1) / waves_per_block;
    fused_window_softmax<<<blocks, 256, 0, stream>>>(X, out);
}